// Round 2
// baseline (787.426 us; speedup 1.0000x reference)
//
#include <hip/hip_runtime.h>

#define B_ 2
#define S_ 2048
#define D_ 768
#define P_ 16
// 768^-0.5 * log2(e): scores kept in log2 domain so exp -> native v_exp_f32
#define SCALE_LOG2 0.0520587723834f

typedef __bf16 bf16x8 __attribute__((ext_vector_type(8)));
typedef float floatx4 __attribute__((ext_vector_type(4)));
using u16 = unsigned short;

__device__ __forceinline__ u16 f2bf(float f) {
    union { float f; unsigned u; } v; v.f = f;
    return (u16)((v.u + 0x7fffu + ((v.u >> 16) & 1u)) >> 16);
}
__device__ __forceinline__ bf16x8 load8(const u16* p) {
    return *reinterpret_cast<const bf16x8*>(p);
}

// ---- normalize patch indices: int64 (little-endian [v,0,...]) or int32 ----
__global__ void norm_idx(const int* __restrict__ raw, int* __restrict__ nidx) {
    bool is64 = (raw[1] == 0);
    int t = threadIdx.x;
    if (t < B_ * P_) nidx[t] = is64 ? raw[2 * t] : raw[t];
}

// ---- convert x (fp32) -> bf16, 8 elements/thread ----
__global__ __launch_bounds__(256) void convert_x(const float* __restrict__ x,
                                                 u16* __restrict__ xb) {
    int i = (blockIdx.x * 256 + threadIdx.x) * 8;
    const float4* p = reinterpret_cast<const float4*>(x + i);
    float4 a = p[0], b = p[1];
    u16 o[8] = {f2bf(a.x), f2bf(a.y), f2bf(a.z), f2bf(a.w),
                f2bf(b.x), f2bf(b.y), f2bf(b.z), f2bf(b.w)};
    *reinterpret_cast<ulonglong2*>(xb + i) = *reinterpret_cast<ulonglong2*>(o);
}

// ---- convert+transpose weights: WT[z][n][k] = bf16(W[z][k][n]) ----
__global__ void transpose_w(const float* __restrict__ Wq, const float* __restrict__ Wk,
                            const float* __restrict__ Wv, u16* __restrict__ WT) {
    __shared__ float tile[32][33];
    int z = blockIdx.z;
    const float* W = z == 0 ? Wq : (z == 1 ? Wk : Wv);
    u16* T = WT + (size_t)z * D_ * D_;
    int x0 = blockIdx.x * 32, y0 = blockIdx.y * 32;
    int tx = threadIdx.x, ty = threadIdx.y;
#pragma unroll
    for (int j = 0; j < 32; j += 8)
        tile[ty + j][tx] = W[(size_t)(y0 + ty + j) * D_ + x0 + tx];
    __syncthreads();
#pragma unroll
    for (int j = 0; j < 32; j += 8)
        T[(size_t)(x0 + ty + j) * D_ + y0 + tx] = f2bf(tile[tx][ty + j]);
}

// ---- fused QKV projection over N=2304 (Q|K|V); per-wave 32x64 tile ----
// V is stored s-chunked: vc[b][s/32][d][s%32] for coalesced PV loads.
__global__ __launch_bounds__(256) void qkv_gemm(
    const u16* __restrict__ xb, const u16* __restrict__ WT,
    const float* __restrict__ bq, const float* __restrict__ bk, const float* __restrict__ bv,
    u16* __restrict__ qws, u16* __restrict__ kws, u16* __restrict__ vcws) {
    int ng0 = blockIdx.y * 64;          // global n in [0, 2304)
    int z = ng0 / 768;                  // 0->q, 1->k, 2->v
    int n0 = ng0 - z * 768;
    const u16* Wt = WT + (size_t)z * D_ * D_;
    const float* bias = z == 0 ? bq : (z == 1 ? bk : bv);
    int wave = threadIdx.x >> 6, lane = threadIdx.x & 63;
    int quad = lane >> 4, l16 = lane & 15;
    int m0 = blockIdx.x * 128 + wave * 32;

    floatx4 acc[2][4];
#pragma unroll
    for (int i = 0; i < 2; ++i)
#pragma unroll
        for (int t = 0; t < 4; ++t) acc[i][t] = (floatx4)(0.0f);

    const u16* xr0 = xb + (size_t)(m0 + l16) * D_;
    const u16* xr1 = xb + (size_t)(m0 + 16 + l16) * D_;
    const u16* wr = Wt + (size_t)(n0 + l16) * D_;
    for (int k = 0; k < D_; k += 32) {
        bf16x8 a0 = load8(xr0 + k + quad * 8);
        bf16x8 a1 = load8(xr1 + k + quad * 8);
#pragma unroll
        for (int t = 0; t < 4; ++t) {
            bf16x8 bfr = load8(wr + (size_t)t * 16 * D_ + k + quad * 8);
            acc[0][t] = __builtin_amdgcn_mfma_f32_16x16x32_bf16(a0, bfr, acc[0][t], 0, 0, 0);
            acc[1][t] = __builtin_amdgcn_mfma_f32_16x16x32_bf16(a1, bfr, acc[1][t], 0, 0, 0);
        }
    }
#pragma unroll
    for (int i = 0; i < 2; ++i) {
#pragma unroll
        for (int t = 0; t < 4; ++t) {
            int n = n0 + t * 16 + l16;
            float bsv = bias[n];
#pragma unroll
            for (int r = 0; r < 4; ++r) {
                int m = m0 + i * 16 + quad * 4 + r;   // C layout: col=lane&15, row=quad*4+r
                u16 h = f2bf(acc[i][t][r] + bsv);
                if (z == 0) {
                    qws[(size_t)m * D_ + n] = h;
                } else if (z == 1) {
                    kws[(size_t)m * D_ + n] = h;
                } else {
                    int bb = m >> 11, s = m & (S_ - 1);
                    // chunked vT: [b][s/32][d][s%32]
                    vcws[(((size_t)bb * (S_ / 32) + (s >> 5)) * D_ + n) * 32 + (s & 31)] = h;
                }
            }
        }
    }
}

// ---- per-patch flash attention v3 ----
// 1024 threads / 16 waves per block; 32 q-rows per block.
// wave = (wq, wk): wq in {0,1} = q-half (16 rows), wk in {0..7} = key-eighth
// (32 keys) of the 256-key chunk for QKT, reused as d-eighth (96 cols) for PV.
// Direct per-wave K loads (wq-pairs share rows via L1); 2 barriers/chunk.
// Per-wave state: O[6]=24 + sc[2]=8 acc floats -> ~80 unified regs, no spill
// under the 128-reg cap from __launch_bounds__(1024,4) (1 block/CU, 50% occ).
__global__ __launch_bounds__(1024, 4) void attn_kernel(
    const int* __restrict__ idx, const u16* __restrict__ qws,
    const u16* __restrict__ kws, const u16* __restrict__ vcws,
    float* __restrict__ out) {
    int b = blockIdx.z, p = blockIdx.y, q0 = blockIdx.x * 32;
    int start = idx[b * P_ + p];
    int end = (p == P_ - 1) ? S_ : idx[b * P_ + p + 1];
    int s32 = start & ~31;
    int e32 = (end + 31) & ~31;          // <= S_ (S_ % 32 == 0)
    int nch = (e32 - s32 + 255) >> 8;

    int tid = threadIdx.x;
    int wave = tid >> 6, lane = tid & 63, quad = lane >> 4, l16 = lane & 15;
    int wq = wave >> 3, wk = wave & 7;
    int row = quad * 4;                   // this quad's 4 C-rows

    __shared__ __align__(16) u16 Plds[2][16][264];   // per q-half; stride 264
    __shared__ float smax[2][8][16], ssum[2][8][16];

    float m_r[4] = {-3e38f, -3e38f, -3e38f, -3e38f};
    float l_r[4] = {0.f, 0.f, 0.f, 0.f};

    floatx4 O[6];
#pragma unroll
    for (int t = 0; t < 6; ++t) O[t] = (floatx4)(0.0f);

    const u16* Qrow = qws + (size_t)(b * S_ + q0 + wq * 16 + l16) * D_ + quad * 8;
    const u16* Kb = kws + (size_t)b * S_ * D_;
    const u16* Vb = vcws + (size_t)b * S_ * D_;     // chunked layout

    for (int c = 0; c < nch; ++c) {
        int kb = s32 + c * 256;
        int rem = e32 - kb; if (rem > 256) rem = 256;   // multiple of 32
        int ng32 = rem >> 5;                            // valid 32-key groups

        // ---- QKT: this wave's 32 keys (2 tiles), kd-outer ----
        int kt0 = kb + wk * 32;
        int c0 = kt0 < e32 - 16 ? kt0 : e32 - 16;       // clamp loads; mask later
        int c1 = kt0 + 16 < e32 - 16 ? kt0 + 16 : e32 - 16;
        const u16* kr0 = Kb + (size_t)(c0 + l16) * D_ + quad * 8;
        const u16* kr1 = Kb + (size_t)(c1 + l16) * D_ + quad * 8;

        floatx4 sc[2];
        sc[0] = (floatx4)(0.0f);
        sc[1] = (floatx4)(0.0f);
        for (int kd = 0; kd < D_; kd += 32) {
            bf16x8 a = load8(Qrow + kd);
            sc[0] = __builtin_amdgcn_mfma_f32_16x16x32_bf16(a, load8(kr0 + kd), sc[0], 0, 0, 0);
            sc[1] = __builtin_amdgcn_mfma_f32_16x16x32_bf16(a, load8(kr1 + kd), sc[1], 0, 0, 0);
        }

        // ---- scale (log2 domain) + mask + per-row max ----
        float rm[4] = {-3e38f, -3e38f, -3e38f, -3e38f};
#pragma unroll
        for (int t = 0; t < 2; ++t) {
            int key = kt0 + t * 16 + l16;
            bool valid = (key >= start) && (key < end);
#pragma unroll
            for (int r = 0; r < 4; ++r) {
                float s = valid ? sc[t][r] * SCALE_LOG2 : -3e38f;
                sc[t][r] = s;
                rm[r] = fmaxf(rm[r], s);
            }
        }
#pragma unroll
        for (int off = 1; off < 16; off <<= 1) {
#pragma unroll
            for (int r = 0; r < 4; ++r) rm[r] = fmaxf(rm[r], __shfl_xor(rm[r], off));
        }
        if (l16 == 0) {
#pragma unroll
            for (int r = 0; r < 4; ++r) smax[wq][wk][row + r] = rm[r];
        }
        __syncthreads();

        // ---- all lanes: new max + alpha (redundant, no serial stage) ----
        float nm[4], al[4];
#pragma unroll
        for (int r = 0; r < 4; ++r) {
            float v = m_r[r];
#pragma unroll
            for (int w = 0; w < 8; ++w) v = fmaxf(v, smax[wq][w][row + r]);
            nm[r] = v;
            al[r] = exp2f(m_r[r] - v);
            m_r[r] = v;
        }

        // ---- P (bf16) -> LDS + row sums; rescale O ----
        float rs[4] = {0.f, 0.f, 0.f, 0.f};
#pragma unroll
        for (int t = 0; t < 2; ++t) {
#pragma unroll
            for (int r = 0; r < 4; ++r) {
                float pv = exp2f(sc[t][r] - nm[r]);   // masked -> exp2(-huge) = 0
                Plds[wq][row + r][wk * 32 + t * 16 + l16] = f2bf(pv);
                rs[r] += pv;
            }
        }
#pragma unroll
        for (int off = 1; off < 16; off <<= 1) {
#pragma unroll
            for (int r = 0; r < 4; ++r) rs[r] += __shfl_xor(rs[r], off);
        }
        if (l16 == 0) {
#pragma unroll
            for (int r = 0; r < 4; ++r) ssum[wq][wk][row + r] = rs[r];
        }
#pragma unroll
        for (int t = 0; t < 6; ++t) {
#pragma unroll
            for (int r = 0; r < 4; ++r) O[t][r] *= al[r];
        }
        __syncthreads();

        // ---- l update (redundant per-quad) + PV over valid 32-key groups ----
#pragma unroll
        for (int r = 0; r < 4; ++r) {
            float s8 = 0.f;
#pragma unroll
            for (int w = 0; w < 8; ++w) s8 += ssum[wq][w][row + r];
            l_r[r] = l_r[r] * al[r] + s8;
        }

        int ch0 = kb >> 5;
        for (int g = 0; g < ng32; ++g) {
            bf16x8 ap = load8(&Plds[wq][l16][g * 32 + quad * 8]);
            const u16* vp = Vb + ((size_t)(ch0 + g) * D_) * 32 + quad * 8;
#pragma unroll
            for (int t = 0; t < 6; ++t) {
                int dcol = wk * 96 + t * 16 + l16;
                bf16x8 bv_ = load8(vp + (size_t)dcol * 32);
                O[t] = __builtin_amdgcn_mfma_f32_16x16x32_bf16(ap, bv_, O[t], 0, 0, 0);
            }
        }
    }

    float inv[4];
#pragma unroll
    for (int r = 0; r < 4; ++r) inv[r] = 1.f / fmaxf(l_r[r], 1e-30f);
    size_t obase = (((size_t)(b * P_ + p) * S_) + q0 + wq * 16) * D_;
#pragma unroll
    for (int t = 0; t < 6; ++t) {
        int dcol = wk * 96 + t * 16 + l16;
#pragma unroll
        for (int r = 0; r < 4; ++r)
            out[obase + (size_t)(row + r) * D_ + dcol] = O[t][r] * inv[r];
    }
}

extern "C" void kernel_launch(void* const* d_in, const int* in_sizes, int n_in,
                              void* d_out, int out_size, void* d_ws, size_t ws_size,
                              hipStream_t stream) {
    const float* x  = (const float*)d_in[0];
    const int* idxraw = (const int*)d_in[1];
    const float* Wq = (const float*)d_in[2];
    const float* bq = (const float*)d_in[3];
    const float* Wk = (const float*)d_in[4];
    const float* bk = (const float*)d_in[5];
    const float* Wv = (const float*)d_in[6];
    const float* bv = (const float*)d_in[7];
    float* out = (float*)d_out;

    u16* ws = (u16*)d_ws;
    const size_t SD = (size_t)B_ * S_ * D_;          // 3,145,728 elements
    u16* xb   = ws;
    u16* qws  = xb + SD;
    u16* kws  = qws + SD;
    u16* vcws = kws + SD;
    u16* wtws = vcws + SD;                           // 3 * 768 * 768 bf16
    int* nidx = (int*)(wtws + (size_t)3 * D_ * D_);

    norm_idx<<<1, 64, 0, stream>>>(idxraw, nidx);
    convert_x<<<dim3(SD / (256 * 8)), dim3(256), 0, stream>>>(x, xb);
    transpose_w<<<dim3(24, 24, 3), dim3(32, 8), 0, stream>>>(Wq, Wk, Wv, wtws);
    qkv_gemm<<<dim3(32, 36), dim3(256), 0, stream>>>(xb, wtws, bq, bk, bv, qws, kws, vcws);
    attn_kernel<<<dim3(64, 16, 2), dim3(1024), 0, stream>>>(nidx, qws, kws, vcws, out);
}

// Round 3
// 605.516 us; speedup vs baseline: 1.3004x; 1.3004x over previous
//
#include <hip/hip_runtime.h>

#define B_ 2
#define S_ 2048
#define D_ 768
#define P_ 16
// 768^-0.5 * log2(e): scores kept in log2 domain so exp -> native v_exp_f32
#define SCALE_LOG2 0.0520587723834f

typedef __bf16 bf16x8 __attribute__((ext_vector_type(8)));
typedef float floatx4 __attribute__((ext_vector_type(4)));
using u16 = unsigned short;

__device__ __forceinline__ u16 f2bf(float f) {
    union { float f; unsigned u; } v; v.f = f;
    return (u16)((v.u + 0x7fffu + ((v.u >> 16) & 1u)) >> 16);
}
__device__ __forceinline__ bf16x8 load8(const u16* p) {
    return *reinterpret_cast<const bf16x8*>(p);
}
// async global->LDS, 16B per lane. LDS dest = wave-uniform base + lane*16.
__device__ __forceinline__ void gld_lds16(u16* l, const u16* g) {
    __builtin_amdgcn_global_load_lds(
        (const __attribute__((address_space(1))) unsigned int*)g,
        (__attribute__((address_space(3))) unsigned int*)l, 16, 0, 0);
}

// ---- normalize patch indices: int64 (little-endian [v,0,...]) or int32 ----
__global__ void norm_idx(const int* __restrict__ raw, int* __restrict__ nidx) {
    bool is64 = (raw[1] == 0);
    int t = threadIdx.x;
    if (t < B_ * P_) nidx[t] = is64 ? raw[2 * t] : raw[t];
}

// ---- convert x (fp32) -> bf16, 8 elements/thread ----
__global__ __launch_bounds__(256) void convert_x(const float* __restrict__ x,
                                                 u16* __restrict__ xb) {
    int i = (blockIdx.x * 256 + threadIdx.x) * 8;
    const float4* p = reinterpret_cast<const float4*>(x + i);
    float4 a = p[0], b = p[1];
    u16 o[8] = {f2bf(a.x), f2bf(a.y), f2bf(a.z), f2bf(a.w),
                f2bf(b.x), f2bf(b.y), f2bf(b.z), f2bf(b.w)};
    *reinterpret_cast<ulonglong2*>(xb + i) = *reinterpret_cast<ulonglong2*>(o);
}

// ---- convert+transpose weights: WT[z][n][k] = bf16(W[z][k][n]) ----
__global__ void transpose_w(const float* __restrict__ Wq, const float* __restrict__ Wk,
                            const float* __restrict__ Wv, u16* __restrict__ WT) {
    __shared__ float tile[32][33];
    int z = blockIdx.z;
    const float* W = z == 0 ? Wq : (z == 1 ? Wk : Wv);
    u16* T = WT + (size_t)z * D_ * D_;
    int x0 = blockIdx.x * 32, y0 = blockIdx.y * 32;
    int tx = threadIdx.x, ty = threadIdx.y;
#pragma unroll
    for (int j = 0; j < 32; j += 8)
        tile[ty + j][tx] = W[(size_t)(y0 + ty + j) * D_ + x0 + tx];
    __syncthreads();
#pragma unroll
    for (int j = 0; j < 32; j += 8)
        T[(size_t)(x0 + ty + j) * D_ + y0 + tx] = f2bf(tile[tx][ty + j]);
}

// ---- fused QKV projection, m97-style staged GEMM ----
// Tile 128m x 64n, BK=32, 256 threads / 4 waves; wave owns 32m x 64n.
// A(x) and B(W^T) tiles staged via global_load_lds(16B), double-buffered,
// one barrier per K-step (2-phase schedule). Output layouts identical to
// the round-0 kernel: q/k row-major [s][d], v transposed [b][d][s].
__global__ __launch_bounds__(256) void qkv_gemm(
    const u16* __restrict__ xb, const u16* __restrict__ WT,
    const float* __restrict__ bq, const float* __restrict__ bk, const float* __restrict__ bv,
    u16* __restrict__ qws, u16* __restrict__ kws, u16* __restrict__ vtws) {
    int ng0 = blockIdx.y * 64;          // global n in [0, 2304)
    int z = ng0 / 768;                  // 0->q, 1->k, 2->v
    int n0 = ng0 - z * 768;
    const u16* Wt = WT + (size_t)z * D_ * D_;
    const float* bias = z == 0 ? bq : (z == 1 ? bk : bv);
    int wave = threadIdx.x >> 6, lane = threadIdx.x & 63;
    int quad = lane >> 4, l16 = lane & 15;
    int m0 = blockIdx.x * 128;

    // LDS tiles: rows of 32 u16 (64 B). A: 128 rows, B: 64 rows. x2 buffers.
    __shared__ __align__(16) u16 Alds[2][128 * 32];
    __shared__ __align__(16) u16 Blds[2][64 * 32];

    // staging map: 1KB chunk per wave-issue = 16 rows; lane -> (row l>>2, 16B piece l&3)
    int rA = lane >> 2, cA = (lane & 3) * 8;
    const u16* Asrc0 = xb + (size_t)(m0 + wave * 32 + rA) * D_ + cA;
    const u16* Asrc1 = Asrc0 + (size_t)16 * D_;
    const u16* Bsrc = Wt + (size_t)(n0 + wave * 16 + rA) * D_ + cA;

#define STAGE(bf, t)                                                       \
    do {                                                                   \
        gld_lds16(Alds[bf] + wave * 1024 + lane * 8, Asrc0 + (t) * 32);    \
        gld_lds16(Alds[bf] + wave * 1024 + 512 + lane * 8, Asrc1 + (t) * 32); \
        gld_lds16(Blds[bf] + wave * 512 + lane * 8, Bsrc + (t) * 32);      \
    } while (0)

    floatx4 acc[2][4];
#pragma unroll
    for (int i = 0; i < 2; ++i)
#pragma unroll
        for (int t = 0; t < 4; ++t) acc[i][t] = (floatx4)(0.0f);

    STAGE(0, 0);                         // prologue
    for (int t = 0; t < 24; ++t) {
        __syncthreads();                 // staged tile t landed; readers of t-1 done
        if (t < 23) STAGE((t + 1) & 1, t + 1);
        const u16* Ab = Alds[t & 1];
        const u16* Bb = Blds[t & 1];
        bf16x8 a0 = load8(Ab + (size_t)(wave * 32 + l16) * 32 + quad * 8);
        bf16x8 a1 = load8(Ab + (size_t)(wave * 32 + 16 + l16) * 32 + quad * 8);
#pragma unroll
        for (int nt = 0; nt < 4; ++nt) {
            bf16x8 bfr = load8(Bb + (size_t)(nt * 16 + l16) * 32 + quad * 8);
            acc[0][nt] = __builtin_amdgcn_mfma_f32_16x16x32_bf16(a0, bfr, acc[0][nt], 0, 0, 0);
            acc[1][nt] = __builtin_amdgcn_mfma_f32_16x16x32_bf16(a1, bfr, acc[1][nt], 0, 0, 0);
        }
    }
#undef STAGE

#pragma unroll
    for (int i = 0; i < 2; ++i) {
#pragma unroll
        for (int t = 0; t < 4; ++t) {
            int n = n0 + t * 16 + l16;
            float bsv = bias[n];
#pragma unroll
            for (int r = 0; r < 4; ++r) {
                int m = m0 + wave * 32 + i * 16 + quad * 4 + r;   // col=lane&15, row=quad*4+r
                u16 h = f2bf(acc[i][t][r] + bsv);
                if (z == 0) {
                    qws[(size_t)m * D_ + n] = h;
                } else if (z == 1) {
                    kws[(size_t)m * D_ + n] = h;
                } else {
                    int bb = m >> 11, s = m & (S_ - 1);
                    vtws[((size_t)bb * D_ + n) * S_ + s] = h;   // vT[b][d][s]
                }
            }
        }
    }
}

// ---- per-patch flash attention, 256-key chunks, 2 barriers/chunk ----
// (byte-identical to the verified 400 us round-0 kernel)
__global__ __launch_bounds__(256) void attn_kernel(
    const int* __restrict__ idx, const u16* __restrict__ qws,
    const u16* __restrict__ kws, const u16* __restrict__ vtws,
    float* __restrict__ out) {
    int b = blockIdx.z, p = blockIdx.y, q0 = blockIdx.x * 16;
    int start = idx[b * P_ + p];
    int end = (p == P_ - 1) ? S_ : idx[b * P_ + p + 1];
    int s32 = start & ~31;
    int e32 = (end + 31) & ~31;          // <= S_ (S_ % 32 == 0)
    int nch = (e32 - s32 + 255) >> 8;

    int tid = threadIdx.x;
    int wave = tid >> 6, lane = tid & 63, quad = lane >> 4, l16 = lane & 15;
    int row = quad * 4;                   // this quad's 4 C-rows

    __shared__ __align__(16) u16 Plds[16][264];   // stride 264: b128 reads 2-way (free)
    __shared__ float smax[4][16], ssum[4][16];

    float m_r[4] = {-3e38f, -3e38f, -3e38f, -3e38f};
    float l_r[4] = {0.f, 0.f, 0.f, 0.f};

    floatx4 O[12];
#pragma unroll
    for (int t = 0; t < 12; ++t) O[t] = (floatx4)(0.0f);

    const u16* Qb = qws + (size_t)(b * S_ + q0) * D_;
    const u16* Kb = kws + (size_t)b * S_ * D_;
    const u16* Vb = vtws + (size_t)b * D_ * S_;

    for (int c = 0; c < nch; ++c) {
        int kb = s32 + c * 256;
        int rem = e32 - kb; if (rem > 256) rem = 256;   // multiple of 32
        int ng32 = rem >> 5;                            // valid 32-key groups

        // ---- QKT: wave's 64 keys (4 tiles), kd-outer (A loaded once/kd) ----
        floatx4 sc[4];
#pragma unroll
        for (int t = 0; t < 4; ++t) sc[t] = (floatx4)(0.0f);
        int ktb[4];
#pragma unroll
        for (int t = 0; t < 4; ++t) {
            int kt = kb + (wave * 4 + t) * 16;
            ktb[t] = kt < e32 - 16 ? kt : e32 - 16;     // clamp loads; mask later
        }
        for (int kd = 0; kd < D_; kd += 32) {
            bf16x8 a = load8(Qb + (size_t)l16 * D_ + kd + quad * 8);
#pragma unroll
            for (int t = 0; t < 4; ++t) {
                bf16x8 bk_ = load8(Kb + (size_t)(ktb[t] + l16) * D_ + kd + quad * 8);
                sc[t] = __builtin_amdgcn_mfma_f32_16x16x32_bf16(a, bk_, sc[t], 0, 0, 0);
            }
        }

        // ---- scale (log2 domain) + mask + per-row max ----
        float rm[4] = {-3e38f, -3e38f, -3e38f, -3e38f};
#pragma unroll
        for (int t = 0; t < 4; ++t) {
            int key = kb + (wave * 4 + t) * 16 + l16;
            bool valid = (key >= start) && (key < end);
#pragma unroll
            for (int r = 0; r < 4; ++r) {
                float s = valid ? sc[t][r] * SCALE_LOG2 : -3e38f;
                sc[t][r] = s;
                rm[r] = fmaxf(rm[r], s);
            }
        }
#pragma unroll
        for (int off = 1; off < 16; off <<= 1) {
#pragma unroll
            for (int r = 0; r < 4; ++r) rm[r] = fmaxf(rm[r], __shfl_xor(rm[r], off));
        }
        if (l16 == 0) {
#pragma unroll
            for (int r = 0; r < 4; ++r) smax[wave][row + r] = rm[r];
        }
        __syncthreads();

        // ---- all lanes: new max + alpha (redundant, no serial stage) ----
        float nm[4], al[4];
#pragma unroll
        for (int r = 0; r < 4; ++r) {
            float v = m_r[r];
#pragma unroll
            for (int w = 0; w < 4; ++w) v = fmaxf(v, smax[w][row + r]);
            nm[r] = v;
            al[r] = exp2f(m_r[r] - v);
            m_r[r] = v;
        }

        // ---- P (bf16) -> LDS + row sums; rescale O ----
        float rs[4] = {0.f, 0.f, 0.f, 0.f};
#pragma unroll
        for (int t = 0; t < 4; ++t) {
#pragma unroll
            for (int r = 0; r < 4; ++r) {
                float pv = exp2f(sc[t][r] - nm[r]);   // masked -> exp2(-huge) = 0
                Plds[row + r][wave * 64 + t * 16 + l16] = f2bf(pv);
                rs[r] += pv;
            }
        }
#pragma unroll
        for (int off = 1; off < 16; off <<= 1) {
#pragma unroll
            for (int r = 0; r < 4; ++r) rs[r] += __shfl_xor(rs[r], off);
        }
        if (l16 == 0) {
#pragma unroll
            for (int r = 0; r < 4; ++r) ssum[wave][row + r] = rs[r];
        }
#pragma unroll
        for (int t = 0; t < 12; ++t) {
#pragma unroll
            for (int r = 0; r < 4; ++r) O[t][r] *= al[r];
        }
        __syncthreads();

        // ---- l update (redundant per-quad) + PV over valid 32-key groups ----
#pragma unroll
        for (int r = 0; r < 4; ++r)
            l_r[r] = l_r[r] * al[r]
                   + ssum[0][row + r] + ssum[1][row + r] + ssum[2][row + r] + ssum[3][row + r];

        for (int g = 0; g < ng32; ++g) {
            bf16x8 ap = load8(&Plds[l16][g * 32 + quad * 8]);
            const u16* vcol = Vb + kb + g * 32 + quad * 8;
#pragma unroll
            for (int t = 0; t < 12; ++t) {
                int dcol = wave * 192 + t * 16 + l16;
                bf16x8 bv_ = load8(vcol + (size_t)dcol * S_);
                O[t] = __builtin_amdgcn_mfma_f32_16x16x32_bf16(ap, bv_, O[t], 0, 0, 0);
            }
        }
    }

    float inv[4];
#pragma unroll
    for (int r = 0; r < 4; ++r) inv[r] = 1.f / fmaxf(l_r[r], 1e-30f);
    size_t obase = (((size_t)(b * P_ + p) * S_) + q0) * D_;
#pragma unroll
    for (int t = 0; t < 12; ++t) {
        int dcol = wave * 192 + t * 16 + l16;
#pragma unroll
        for (int r = 0; r < 4; ++r)
            out[obase + (size_t)(row + r) * D_ + dcol] = O[t][r] * inv[r];
    }
}

extern "C" void kernel_launch(void* const* d_in, const int* in_sizes, int n_in,
                              void* d_out, int out_size, void* d_ws, size_t ws_size,
                              hipStream_t stream) {
    const float* x  = (const float*)d_in[0];
    const int* idxraw = (const int*)d_in[1];
    const float* Wq = (const float*)d_in[2];
    const float* bq = (const float*)d_in[3];
    const float* Wk = (const float*)d_in[4];
    const float* bk = (const float*)d_in[5];
    const float* Wv = (const float*)d_in[6];
    const float* bv = (const float*)d_in[7];
    float* out = (float*)d_out;

    u16* ws = (u16*)d_ws;
    const size_t SD = (size_t)B_ * S_ * D_;          // 3,145,728 elements
    u16* xb   = ws;
    u16* qws  = xb + SD;
    u16* kws  = qws + SD;
    u16* vtws = kws + SD;
    u16* wtws = vtws + SD;                           // 3 * 768 * 768 bf16
    int* nidx = (int*)(wtws + (size_t)3 * D_ * D_);

    norm_idx<<<1, 64, 0, stream>>>(idxraw, nidx);
    convert_x<<<dim3(SD / (256 * 8)), dim3(256), 0, stream>>>(x, xb);
    transpose_w<<<dim3(24, 24, 3), dim3(32, 8), 0, stream>>>(Wq, Wk, Wv, wtws);
    qkv_gemm<<<dim3(32, 36), dim3(256), 0, stream>>>(xb, wtws, bq, bk, bv, qws, kws, vtws);
    attn_kernel<<<dim3(128, 16, 2), dim3(256), 0, stream>>>(nidx, qws, kws, vtws, out);
}

// Round 4
// 520.745 us; speedup vs baseline: 1.5121x; 1.1628x over previous
//
#include <hip/hip_runtime.h>

#define B_ 2
#define S_ 2048
#define D_ 768
#define P_ 16
// 768^-0.5 * log2(e): scores kept in log2 domain so exp -> native v_exp_f32
#define SCALE_LOG2 0.0520587723834f

typedef __bf16 bf16x8 __attribute__((ext_vector_type(8)));
typedef float floatx4 __attribute__((ext_vector_type(4)));
using u16 = unsigned short;

__device__ __forceinline__ u16 f2bf(float f) {
    union { float f; unsigned u; } v; v.f = f;
    return (u16)((v.u + 0x7fffu + ((v.u >> 16) & 1u)) >> 16);
}
__device__ __forceinline__ bf16x8 load8(const u16* p) {
    return *reinterpret_cast<const bf16x8*>(p);
}
// async global->LDS, 16B per lane. LDS dest = wave-uniform base + lane*16.
__device__ __forceinline__ void gld_lds16(u16* l, const u16* g) {
    __builtin_amdgcn_global_load_lds(
        (const __attribute__((address_space(1))) unsigned int*)g,
        (__attribute__((address_space(3))) unsigned int*)l, 16, 0, 0);
}

// Fragment-tiled layout for Q/K: [b][s/16][d/32][16][32], element offset:
//   (b*128 + (s>>4)) * 12288 + (d>>5)*512 + (s&15)*32 + (d&31)
// -> one MFMA A/B fragment (16 rows x 32 kd) is a contiguous 1KB block.
__device__ __forceinline__ size_t qk_tile(int b, int s16, int d32) {
    return ((size_t)(b * 128 + s16)) * 12288 + (size_t)d32 * 512;
}

// ---- normalize patch indices: int64 (little-endian [v,0,...]) or int32 ----
__global__ void norm_idx(const int* __restrict__ raw, int* __restrict__ nidx) {
    bool is64 = (raw[1] == 0);
    int t = threadIdx.x;
    if (t < B_ * P_) nidx[t] = is64 ? raw[2 * t] : raw[t];
}

// ---- convert x (fp32) -> bf16, 8 elements/thread ----
__global__ __launch_bounds__(256) void convert_x(const float* __restrict__ x,
                                                 u16* __restrict__ xb) {
    int i = (blockIdx.x * 256 + threadIdx.x) * 8;
    const float4* p = reinterpret_cast<const float4*>(x + i);
    float4 a = p[0], b = p[1];
    u16 o[8] = {f2bf(a.x), f2bf(a.y), f2bf(a.z), f2bf(a.w),
                f2bf(b.x), f2bf(b.y), f2bf(b.z), f2bf(b.w)};
    *reinterpret_cast<ulonglong2*>(xb + i) = *reinterpret_cast<ulonglong2*>(o);
}

// ---- convert+transpose weights: WT[z][n][k] = bf16(W[z][k][n]) ----
__global__ void transpose_w(const float* __restrict__ Wq, const float* __restrict__ Wk,
                            const float* __restrict__ Wv, u16* __restrict__ WT) {
    __shared__ float tile[32][33];
    int z = blockIdx.z;
    const float* W = z == 0 ? Wq : (z == 1 ? Wk : Wv);
    u16* T = WT + (size_t)z * D_ * D_;
    int x0 = blockIdx.x * 32, y0 = blockIdx.y * 32;
    int tx = threadIdx.x, ty = threadIdx.y;
#pragma unroll
    for (int j = 0; j < 32; j += 8)
        tile[ty + j][tx] = W[(size_t)(y0 + ty + j) * D_ + x0 + tx];
    __syncthreads();
#pragma unroll
    for (int j = 0; j < 32; j += 8)
        T[(size_t)(x0 + ty + j) * D_ + y0 + tx] = f2bf(tile[tx][ty + j]);
}

// ---- fused QKV projection, m97-style staged GEMM ----
// Tile 128m x 64n, BK=32, 256 threads / 4 waves; wave owns 32m x 64n.
// Outputs written in attn-native layouts:
//   Q,K: fragment-tiled [b][s/16][d/32][16][32]
//   V:   s-chunked      [b][s/32][d][32]
__global__ __launch_bounds__(256) void qkv_gemm(
    const u16* __restrict__ xb, const u16* __restrict__ WT,
    const float* __restrict__ bq, const float* __restrict__ bk, const float* __restrict__ bv,
    u16* __restrict__ qws, u16* __restrict__ kws, u16* __restrict__ vcws) {
    int ng0 = blockIdx.y * 64;          // global n in [0, 2304)
    int z = ng0 / 768;                  // 0->q, 1->k, 2->v
    int n0 = ng0 - z * 768;
    const u16* Wt = WT + (size_t)z * D_ * D_;
    const float* bias = z == 0 ? bq : (z == 1 ? bk : bv);
    int wave = threadIdx.x >> 6, lane = threadIdx.x & 63;
    int quad = lane >> 4, l16 = lane & 15;
    int m0 = blockIdx.x * 128;

    __shared__ __align__(16) u16 Alds[2][128 * 32];
    __shared__ __align__(16) u16 Blds[2][64 * 32];

    int rA = lane >> 2, cA = (lane & 3) * 8;
    const u16* Asrc0 = xb + (size_t)(m0 + wave * 32 + rA) * D_ + cA;
    const u16* Asrc1 = Asrc0 + (size_t)16 * D_;
    const u16* Bsrc = Wt + (size_t)(n0 + wave * 16 + rA) * D_ + cA;

#define STAGE(bf, t)                                                       \
    do {                                                                   \
        gld_lds16(Alds[bf] + wave * 1024 + lane * 8, Asrc0 + (t) * 32);    \
        gld_lds16(Alds[bf] + wave * 1024 + 512 + lane * 8, Asrc1 + (t) * 32); \
        gld_lds16(Blds[bf] + wave * 512 + lane * 8, Bsrc + (t) * 32);      \
    } while (0)

    floatx4 acc[2][4];
#pragma unroll
    for (int i = 0; i < 2; ++i)
#pragma unroll
        for (int t = 0; t < 4; ++t) acc[i][t] = (floatx4)(0.0f);

    STAGE(0, 0);                         // prologue
    for (int t = 0; t < 24; ++t) {
        __syncthreads();                 // staged tile t landed; readers of t-1 done
        if (t < 23) STAGE((t + 1) & 1, t + 1);
        const u16* Ab = Alds[t & 1];
        const u16* Bb = Blds[t & 1];
        bf16x8 a0 = load8(Ab + (size_t)(wave * 32 + l16) * 32 + quad * 8);
        bf16x8 a1 = load8(Ab + (size_t)(wave * 32 + 16 + l16) * 32 + quad * 8);
#pragma unroll
        for (int nt = 0; nt < 4; ++nt) {
            bf16x8 bfr = load8(Bb + (size_t)(nt * 16 + l16) * 32 + quad * 8);
            acc[0][nt] = __builtin_amdgcn_mfma_f32_16x16x32_bf16(a0, bfr, acc[0][nt], 0, 0, 0);
            acc[1][nt] = __builtin_amdgcn_mfma_f32_16x16x32_bf16(a1, bfr, acc[1][nt], 0, 0, 0);
        }
    }
#undef STAGE

#pragma unroll
    for (int i = 0; i < 2; ++i) {
#pragma unroll
        for (int t = 0; t < 4; ++t) {
            int n = n0 + t * 16 + l16;
            float bsv = bias[n];
#pragma unroll
            for (int r = 0; r < 4; ++r) {
                int m = m0 + wave * 32 + i * 16 + quad * 4 + r;   // col=lane&15, row=quad*4+r
                u16 h = f2bf(acc[i][t][r] + bsv);
                int bb = m >> 11, s = m & (S_ - 1);
                if (z == 2) {
                    // s-chunked vT: [b][s/32][d][s%32]
                    vcws[(((size_t)bb * (S_ / 32) + (s >> 5)) * D_ + n) * 32 + (s & 31)] = h;
                } else {
                    size_t off = qk_tile(bb, s >> 4, n >> 5) + (size_t)(s & 15) * 32 + (n & 31);
                    (z == 0 ? qws : kws)[off] = h;
                }
            }
        }
    }
}

// ---- per-patch flash attention, 256-key chunks, 2 barriers/chunk ----
// Round-0 geometry/schedule; all global loads now contiguous 1KB fragments.
__global__ __launch_bounds__(256) void attn_kernel(
    const int* __restrict__ idx, const u16* __restrict__ qws,
    const u16* __restrict__ kws, const u16* __restrict__ vcws,
    float* __restrict__ out) {
    int b = blockIdx.z, p = blockIdx.y, q0 = blockIdx.x * 16;
    int start = idx[b * P_ + p];
    int end = (p == P_ - 1) ? S_ : idx[b * P_ + p + 1];
    int s32 = start & ~31;
    int e32 = (end + 31) & ~31;          // <= S_ (S_ % 32 == 0)
    int nch = (e32 - s32 + 255) >> 8;

    int tid = threadIdx.x;
    int wave = tid >> 6, lane = tid & 63, quad = lane >> 4, l16 = lane & 15;
    int row = quad * 4;                   // this quad's 4 C-rows
    int frag = l16 * 32 + quad * 8;       // within-fragment offset (16x32 tile)

    __shared__ __align__(16) u16 Plds[16][264];   // stride 264: b128 reads 2-way (free)
    __shared__ float smax[4][16], ssum[4][16];

    float m_r[4] = {-3e38f, -3e38f, -3e38f, -3e38f};
    float l_r[4] = {0.f, 0.f, 0.f, 0.f};

    floatx4 O[12];
#pragma unroll
    for (int t = 0; t < 12; ++t) O[t] = (floatx4)(0.0f);

    const u16* Qt = qws + qk_tile(b, q0 >> 4, 0) + frag;   // +kd32*512 walks kd
    const u16* Vb = vcws + (size_t)b * S_ * D_;            // chunked layout

    for (int c = 0; c < nch; ++c) {
        int kb = s32 + c * 256;
        int rem = e32 - kb; if (rem > 256) rem = 256;   // multiple of 32
        int ng32 = rem >> 5;                            // valid 32-key groups

        // ---- QKT: wave's 64 keys (4 tiles), kd-outer (A loaded once/kd) ----
        floatx4 sc[4];
#pragma unroll
        for (int t = 0; t < 4; ++t) sc[t] = (floatx4)(0.0f);
        const u16* kt_ptr[4];
#pragma unroll
        for (int t = 0; t < 4; ++t) {
            int kt = kb + (wave * 4 + t) * 16;
            kt = kt < e32 - 16 ? kt : e32 - 16;         // clamp loads (16-aligned); mask later
            kt_ptr[t] = kws + qk_tile(b, kt >> 4, 0) + frag;
        }
        for (int kd = 0; kd < 24; ++kd) {
            bf16x8 a = load8(Qt + kd * 512);
#pragma unroll
            for (int t = 0; t < 4; ++t) {
                bf16x8 bk_ = load8(kt_ptr[t] + kd * 512);
                sc[t] = __builtin_amdgcn_mfma_f32_16x16x32_bf16(a, bk_, sc[t], 0, 0, 0);
            }
        }

        // ---- scale (log2 domain) + mask + per-row max ----
        float rm[4] = {-3e38f, -3e38f, -3e38f, -3e38f};
#pragma unroll
        for (int t = 0; t < 4; ++t) {
            int key = kb + (wave * 4 + t) * 16 + l16;
            bool valid = (key >= start) && (key < end);
#pragma unroll
            for (int r = 0; r < 4; ++r) {
                float s = valid ? sc[t][r] * SCALE_LOG2 : -3e38f;
                sc[t][r] = s;
                rm[r] = fmaxf(rm[r], s);
            }
        }
#pragma unroll
        for (int off = 1; off < 16; off <<= 1) {
#pragma unroll
            for (int r = 0; r < 4; ++r) rm[r] = fmaxf(rm[r], __shfl_xor(rm[r], off));
        }
        if (l16 == 0) {
#pragma unroll
            for (int r = 0; r < 4; ++r) smax[wave][row + r] = rm[r];
        }
        __syncthreads();

        // ---- all lanes: new max + alpha (redundant, no serial stage) ----
        float nm[4], al[4];
#pragma unroll
        for (int r = 0; r < 4; ++r) {
            float v = m_r[r];
#pragma unroll
            for (int w = 0; w < 4; ++w) v = fmaxf(v, smax[w][row + r]);
            nm[r] = v;
            al[r] = exp2f(m_r[r] - v);
            m_r[r] = v;
        }

        // ---- P (bf16) -> LDS + row sums; rescale O ----
        float rs[4] = {0.f, 0.f, 0.f, 0.f};
#pragma unroll
        for (int t = 0; t < 4; ++t) {
#pragma unroll
            for (int r = 0; r < 4; ++r) {
                float pv = exp2f(sc[t][r] - nm[r]);   // masked -> exp2(-huge) = 0
                Plds[row + r][wave * 64 + t * 16 + l16] = f2bf(pv);
                rs[r] += pv;
            }
        }
#pragma unroll
        for (int off = 1; off < 16; off <<= 1) {
#pragma unroll
            for (int r = 0; r < 4; ++r) rs[r] += __shfl_xor(rs[r], off);
        }
        if (l16 == 0) {
#pragma unroll
            for (int r = 0; r < 4; ++r) ssum[wave][row + r] = rs[r];
        }
#pragma unroll
        for (int t = 0; t < 12; ++t) {
#pragma unroll
            for (int r = 0; r < 4; ++r) O[t][r] *= al[r];
        }
        __syncthreads();

        // ---- l update (redundant per-quad) + PV over valid 32-key groups ----
#pragma unroll
        for (int r = 0; r < 4; ++r)
            l_r[r] = l_r[r] * al[r]
                   + ssum[0][row + r] + ssum[1][row + r] + ssum[2][row + r] + ssum[3][row + r];

        int ch0 = kb >> 5;
        for (int g = 0; g < ng32; ++g) {
            bf16x8 ap = load8(&Plds[l16][g * 32 + quad * 8]);
            const u16* vp = Vb + ((size_t)(ch0 + g) * D_) * 32 + quad * 8;
#pragma unroll
            for (int t = 0; t < 12; ++t) {
                int dcol = wave * 192 + t * 16 + l16;
                bf16x8 bv_ = load8(vp + (size_t)dcol * 32);
                O[t] = __builtin_amdgcn_mfma_f32_16x16x32_bf16(ap, bv_, O[t], 0, 0, 0);
            }
        }
    }

    float inv[4];
#pragma unroll
    for (int r = 0; r < 4; ++r) inv[r] = 1.f / fmaxf(l_r[r], 1e-30f);
    size_t obase = (((size_t)(b * P_ + p) * S_) + q0) * D_;
#pragma unroll
    for (int t = 0; t < 12; ++t) {
        int dcol = wave * 192 + t * 16 + l16;
#pragma unroll
        for (int r = 0; r < 4; ++r)
            out[obase + (size_t)(row + r) * D_ + dcol] = O[t][r] * inv[r];
    }
}

extern "C" void kernel_launch(void* const* d_in, const int* in_sizes, int n_in,
                              void* d_out, int out_size, void* d_ws, size_t ws_size,
                              hipStream_t stream) {
    const float* x  = (const float*)d_in[0];
    const int* idxraw = (const int*)d_in[1];
    const float* Wq = (const float*)d_in[2];
    const float* bq = (const float*)d_in[3];
    const float* Wk = (const float*)d_in[4];
    const float* bk = (const float*)d_in[5];
    const float* Wv = (const float*)d_in[6];
    const float* bv = (const float*)d_in[7];
    float* out = (float*)d_out;

    u16* ws = (u16*)d_ws;
    const size_t SD = (size_t)B_ * S_ * D_;          // 3,145,728 elements
    u16* xb   = ws;
    u16* qws  = xb + SD;
    u16* kws  = qws + SD;
    u16* vcws = kws + SD;
    u16* wtws = vcws + SD;                           // 3 * 768 * 768 bf16
    int* nidx = (int*)(wtws + (size_t)3 * D_ * D_);

    norm_idx<<<1, 64, 0, stream>>>(idxraw, nidx);
    convert_x<<<dim3(SD / (256 * 8)), dim3(256), 0, stream>>>(x, xb);
    transpose_w<<<dim3(24, 24, 3), dim3(32, 8), 0, stream>>>(Wq, Wk, Wv, wtws);
    qkv_gemm<<<dim3(32, 36), dim3(256), 0, stream>>>(xb, wtws, bq, bk, bv, qws, kws, vcws);
    attn_kernel<<<dim3(128, 16, 2), dim3(256), 0, stream>>>(nidx, qws, kws, vcws, out);
}

// Round 5
// 482.697 us; speedup vs baseline: 1.6313x; 1.0788x over previous
//
#include <hip/hip_runtime.h>

#define B_ 2
#define S_ 2048
#define D_ 768
#define P_ 16
// 768^-0.5 * log2(e): scores kept in log2 domain so exp -> native v_exp_f32
#define SCALE_LOG2 0.0520587723834f

typedef __bf16 bf16x8 __attribute__((ext_vector_type(8)));
typedef float floatx4 __attribute__((ext_vector_type(4)));
using u16 = unsigned short;

__device__ __forceinline__ u16 f2bf(float f) {
    union { float f; unsigned u; } v; v.f = f;
    return (u16)((v.u + 0x7fffu + ((v.u >> 16) & 1u)) >> 16);
}
__device__ __forceinline__ bf16x8 load8(const u16* p) {
    return *reinterpret_cast<const bf16x8*>(p);
}
// async global->LDS, 16B per lane. LDS dest = wave-uniform base + lane*16.
__device__ __forceinline__ void gld_lds16(u16* l, const u16* g) {
    __builtin_amdgcn_global_load_lds(
        (const __attribute__((address_space(1))) unsigned int*)g,
        (__attribute__((address_space(3))) unsigned int*)l, 16, 0, 0);
}

// Fragment-tiled layout for Q/K: [b][s/16][d/32][16][32], element offset:
//   (b*128 + (s>>4)) * 12288 + (d>>5)*512 + (s&15)*32 + (d&31)
// -> one MFMA A/B fragment (16 rows x 32 kd) is a contiguous 1KB block.
__device__ __forceinline__ size_t qk_tile(int b, int s16, int d32) {
    return ((size_t)(b * 128 + s16)) * 12288 + (size_t)d32 * 512;
}

// ---- normalize patch indices: int64 (little-endian [v,0,...]) or int32 ----
__global__ void norm_idx(const int* __restrict__ raw, int* __restrict__ nidx) {
    bool is64 = (raw[1] == 0);
    int t = threadIdx.x;
    if (t < B_ * P_) nidx[t] = is64 ? raw[2 * t] : raw[t];
}

// ---- convert x (fp32) -> bf16, 8 elements/thread ----
__global__ __launch_bounds__(256) void convert_x(const float* __restrict__ x,
                                                 u16* __restrict__ xb) {
    int i = (blockIdx.x * 256 + threadIdx.x) * 8;
    const float4* p = reinterpret_cast<const float4*>(x + i);
    float4 a = p[0], b = p[1];
    u16 o[8] = {f2bf(a.x), f2bf(a.y), f2bf(a.z), f2bf(a.w),
                f2bf(b.x), f2bf(b.y), f2bf(b.z), f2bf(b.w)};
    *reinterpret_cast<ulonglong2*>(xb + i) = *reinterpret_cast<ulonglong2*>(o);
}

// ---- convert+transpose weights: WT[z][n][k] = bf16(W[z][k][n]) ----
__global__ void transpose_w(const float* __restrict__ Wq, const float* __restrict__ Wk,
                            const float* __restrict__ Wv, u16* __restrict__ WT) {
    __shared__ float tile[32][33];
    int z = blockIdx.z;
    const float* W = z == 0 ? Wq : (z == 1 ? Wk : Wv);
    u16* T = WT + (size_t)z * D_ * D_;
    int x0 = blockIdx.x * 32, y0 = blockIdx.y * 32;
    int tx = threadIdx.x, ty = threadIdx.y;
#pragma unroll
    for (int j = 0; j < 32; j += 8)
        tile[ty + j][tx] = W[(size_t)(y0 + ty + j) * D_ + x0 + tx];
    __syncthreads();
#pragma unroll
    for (int j = 0; j < 32; j += 8)
        T[(size_t)(x0 + ty + j) * D_ + y0 + tx] = f2bf(tile[tx][ty + j]);
}

// ---- fused QKV projection, staged GEMM, tile 128m x 128n, BK=32 ----
// 256 threads / 4 waves; wave owns 32m x 128n (16 MFMA : 10 ds_read_b128/step).
// Outputs written in attn-native layouts:
//   Q,K: fragment-tiled [b][s/16][d/32][16][32]
//   V:   s-chunked      [b][s/32][d][32]
__global__ __launch_bounds__(256) void qkv_gemm(
    const u16* __restrict__ xb, const u16* __restrict__ WT,
    const float* __restrict__ bq, const float* __restrict__ bk, const float* __restrict__ bv,
    u16* __restrict__ qws, u16* __restrict__ kws, u16* __restrict__ vcws) {
    int ng0 = blockIdx.y * 128;         // global n in [0, 2304); 128 | 768
    int z = ng0 / 768;                  // 0->q, 1->k, 2->v
    int n0 = ng0 - z * 768;
    const u16* Wt = WT + (size_t)z * D_ * D_;
    const float* bias = z == 0 ? bq : (z == 1 ? bk : bv);
    int wave = threadIdx.x >> 6, lane = threadIdx.x & 63;
    int quad = lane >> 4, l16 = lane & 15;
    int m0 = blockIdx.x * 128;

    __shared__ __align__(16) u16 Alds[2][128 * 32];
    __shared__ __align__(16) u16 Blds[2][128 * 32];

    int rA = lane >> 2, cA = (lane & 3) * 8;
    const u16* Asrc0 = xb + (size_t)(m0 + wave * 32 + rA) * D_ + cA;
    const u16* Asrc1 = Asrc0 + (size_t)16 * D_;
    const u16* Bsrc0 = Wt + (size_t)(n0 + wave * 32 + rA) * D_ + cA;
    const u16* Bsrc1 = Bsrc0 + (size_t)16 * D_;

#define STAGE(bf, t)                                                          \
    do {                                                                      \
        gld_lds16(Alds[bf] + wave * 1024 + lane * 8, Asrc0 + (t) * 32);       \
        gld_lds16(Alds[bf] + wave * 1024 + 512 + lane * 8, Asrc1 + (t) * 32); \
        gld_lds16(Blds[bf] + wave * 1024 + lane * 8, Bsrc0 + (t) * 32);       \
        gld_lds16(Blds[bf] + wave * 1024 + 512 + lane * 8, Bsrc1 + (t) * 32); \
    } while (0)

    floatx4 acc[2][8];
#pragma unroll
    for (int i = 0; i < 2; ++i)
#pragma unroll
        for (int t = 0; t < 8; ++t) acc[i][t] = (floatx4)(0.0f);

    STAGE(0, 0);                         // prologue
    for (int t = 0; t < 24; ++t) {
        __syncthreads();                 // staged tile t landed; readers of t-1 done
        if (t < 23) STAGE((t + 1) & 1, t + 1);
        const u16* Ab = Alds[t & 1];
        const u16* Bb = Blds[t & 1];
        bf16x8 a0 = load8(Ab + (size_t)(wave * 32 + l16) * 32 + quad * 8);
        bf16x8 a1 = load8(Ab + (size_t)(wave * 32 + 16 + l16) * 32 + quad * 8);
#pragma unroll
        for (int nt = 0; nt < 8; ++nt) {
            bf16x8 bfr = load8(Bb + (size_t)(nt * 16 + l16) * 32 + quad * 8);
            acc[0][nt] = __builtin_amdgcn_mfma_f32_16x16x32_bf16(a0, bfr, acc[0][nt], 0, 0, 0);
            acc[1][nt] = __builtin_amdgcn_mfma_f32_16x16x32_bf16(a1, bfr, acc[1][nt], 0, 0, 0);
        }
    }
#undef STAGE

#pragma unroll
    for (int i = 0; i < 2; ++i) {
#pragma unroll
        for (int t = 0; t < 8; ++t) {
            int n = n0 + t * 16 + l16;
            float bsv = bias[n];
#pragma unroll
            for (int r = 0; r < 4; ++r) {
                int m = m0 + wave * 32 + i * 16 + quad * 4 + r;   // col=lane&15, row=quad*4+r
                u16 h = f2bf(acc[i][t][r] + bsv);
                int bb = m >> 11, s = m & (S_ - 1);
                if (z == 2) {
                    // s-chunked vT: [b][s/32][d][s%32]
                    vcws[(((size_t)bb * (S_ / 32) + (s >> 5)) * D_ + n) * 32 + (s & 31)] = h;
                } else {
                    size_t off = qk_tile(bb, s >> 4, n >> 5) + (size_t)(s & 15) * 32 + (n & 31);
                    (z == 0 ? qws : kws)[off] = h;
                }
            }
        }
    }
}

// ---- per-patch flash attention, 256-key chunks, 2 barriers/chunk ----
// Round-4 geometry/schedule; QKT tiles assigned dynamically: tile j (16 keys,
// j < ng16 = rem/16) goes to wave j%4 -> zero clamped-redundant MFMA/loads.
__global__ __launch_bounds__(256) void attn_kernel(
    const int* __restrict__ idx, const u16* __restrict__ qws,
    const u16* __restrict__ kws, const u16* __restrict__ vcws,
    float* __restrict__ out) {
    int b = blockIdx.z, p = blockIdx.y, q0 = blockIdx.x * 16;
    int start = idx[b * P_ + p];
    int end = (p == P_ - 1) ? S_ : idx[b * P_ + p + 1];
    int s32 = start & ~31;
    int e32 = (end + 31) & ~31;          // <= S_ (S_ % 32 == 0)
    int nch = (e32 - s32 + 255) >> 8;

    int tid = threadIdx.x;
    int wave = tid >> 6, lane = tid & 63, quad = lane >> 4, l16 = lane & 15;
    int row = quad * 4;                   // this quad's 4 C-rows
    int frag = l16 * 32 + quad * 8;       // within-fragment offset (16x32 tile)

    __shared__ __align__(16) u16 Plds[16][264];   // stride 264: b128 reads 2-way (free)
    __shared__ float smax[4][16], ssum[4][16];

    float m_r[4] = {-3e38f, -3e38f, -3e38f, -3e38f};
    float l_r[4] = {0.f, 0.f, 0.f, 0.f};

    floatx4 O[12];
#pragma unroll
    for (int t = 0; t < 12; ++t) O[t] = (floatx4)(0.0f);

    const u16* Qt = qws + qk_tile(b, q0 >> 4, 0) + frag;   // +kd*512 walks kd
    const u16* Vb = vcws + (size_t)b * S_ * D_;            // chunked layout

    for (int c = 0; c < nch; ++c) {
        int kb = s32 + c * 256;
        int rem = e32 - kb; if (rem > 256) rem = 256;   // multiple of 32
        int ng32 = rem >> 5;                            // valid 32-key groups
        int ng16 = rem >> 4;                            // valid 16-key tiles
        int nt = (ng16 - wave + 3) >> 2;                // this wave's tile count (j = 4t+wave)

        // ---- QKT: only real tiles, kd-outer (A loaded once/kd) ----
        floatx4 sc[4];
#pragma unroll
        for (int t = 0; t < 4; ++t) sc[t] = (floatx4)(0.0f);
        if (nt > 0) {
            const u16* kt_ptr[4];
#pragma unroll
            for (int t = 0; t < 4; ++t)
                if (t < nt)
                    kt_ptr[t] = kws + qk_tile(b, (kb >> 4) + 4 * t + wave, 0) + frag;
            for (int kd = 0; kd < 24; ++kd) {
                bf16x8 a = load8(Qt + kd * 512);
#pragma unroll
                for (int t = 0; t < 4; ++t)
                    if (t < nt) {
                        bf16x8 bk_ = load8(kt_ptr[t] + kd * 512);
                        sc[t] = __builtin_amdgcn_mfma_f32_16x16x32_bf16(a, bk_, sc[t], 0, 0, 0);
                    }
            }
        }

        // ---- scale (log2 domain) + mask + per-row max ----
        float rm[4] = {-3e38f, -3e38f, -3e38f, -3e38f};
#pragma unroll
        for (int t = 0; t < 4; ++t)
            if (t < nt) {
                int key = kb + (4 * t + wave) * 16 + l16;
                bool valid = (key >= start) && (key < end);
#pragma unroll
                for (int r = 0; r < 4; ++r) {
                    float s = valid ? sc[t][r] * SCALE_LOG2 : -3e38f;
                    sc[t][r] = s;
                    rm[r] = fmaxf(rm[r], s);
                }
            }
#pragma unroll
        for (int off = 1; off < 16; off <<= 1) {
#pragma unroll
            for (int r = 0; r < 4; ++r) rm[r] = fmaxf(rm[r], __shfl_xor(rm[r], off));
        }
        if (l16 == 0) {
#pragma unroll
            for (int r = 0; r < 4; ++r) smax[wave][row + r] = rm[r];
        }
        __syncthreads();

        // ---- all lanes: new max + alpha (redundant, no serial stage) ----
        float nm[4], al[4];
#pragma unroll
        for (int r = 0; r < 4; ++r) {
            float v = m_r[r];
#pragma unroll
            for (int w = 0; w < 4; ++w) v = fmaxf(v, smax[w][row + r]);
            nm[r] = v;
            al[r] = exp2f(m_r[r] - v);
            m_r[r] = v;
        }

        // ---- P (bf16) -> LDS + row sums; rescale O ----
        float rs[4] = {0.f, 0.f, 0.f, 0.f};
#pragma unroll
        for (int t = 0; t < 4; ++t)
            if (t < nt) {
#pragma unroll
                for (int r = 0; r < 4; ++r) {
                    float pv = exp2f(sc[t][r] - nm[r]);   // masked -> exp2(-huge) = 0
                    Plds[row + r][(4 * t + wave) * 16 + l16] = f2bf(pv);
                    rs[r] += pv;
                }
            }
#pragma unroll
        for (int off = 1; off < 16; off <<= 1) {
#pragma unroll
            for (int r = 0; r < 4; ++r) rs[r] += __shfl_xor(rs[r], off);
        }
        if (l16 == 0) {
#pragma unroll
            for (int r = 0; r < 4; ++r) ssum[wave][row + r] = rs[r];
        }
#pragma unroll
        for (int t = 0; t < 12; ++t) {
#pragma unroll
            for (int r = 0; r < 4; ++r) O[t][r] *= al[r];
        }
        __syncthreads();

        // ---- l update (redundant per-quad) + PV over valid 32-key groups ----
#pragma unroll
        for (int r = 0; r < 4; ++r)
            l_r[r] = l_r[r] * al[r]
                   + ssum[0][row + r] + ssum[1][row + r] + ssum[2][row + r] + ssum[3][row + r];

        int ch0 = kb >> 5;
        for (int g = 0; g < ng32; ++g) {
            bf16x8 ap = load8(&Plds[l16][g * 32 + quad * 8]);
            const u16* vp = Vb + ((size_t)(ch0 + g) * D_) * 32 + quad * 8;
#pragma unroll
            for (int t = 0; t < 12; ++t) {
                int dcol = wave * 192 + t * 16 + l16;
                bf16x8 bv_ = load8(vp + (size_t)dcol * 32);
                O[t] = __builtin_amdgcn_mfma_f32_16x16x32_bf16(ap, bv_, O[t], 0, 0, 0);
            }
        }
    }

    float inv[4];
#pragma unroll
    for (int r = 0; r < 4; ++r) inv[r] = 1.f / fmaxf(l_r[r], 1e-30f);
    size_t obase = (((size_t)(b * P_ + p) * S_) + q0) * D_;
#pragma unroll
    for (int t = 0; t < 12; ++t) {
        int dcol = wave * 192 + t * 16 + l16;
#pragma unroll
        for (int r = 0; r < 4; ++r)
            out[obase + (size_t)(row + r) * D_ + dcol] = O[t][r] * inv[r];
    }
}

extern "C" void kernel_launch(void* const* d_in, const int* in_sizes, int n_in,
                              void* d_out, int out_size, void* d_ws, size_t ws_size,
                              hipStream_t stream) {
    const float* x  = (const float*)d_in[0];
    const int* idxraw = (const int*)d_in[1];
    const float* Wq = (const float*)d_in[2];
    const float* bq = (const float*)d_in[3];
    const float* Wk = (const float*)d_in[4];
    const float* bk = (const float*)d_in[5];
    const float* Wv = (const float*)d_in[6];
    const float* bv = (const float*)d_in[7];
    float* out = (float*)d_out;

    u16* ws = (u16*)d_ws;
    const size_t SD = (size_t)B_ * S_ * D_;          // 3,145,728 elements
    u16* xb   = ws;
    u16* qws  = xb + SD;
    u16* kws  = qws + SD;
    u16* vcws = kws + SD;
    u16* wtws = vcws + SD;                           // 3 * 768 * 768 bf16
    int* nidx = (int*)(wtws + (size_t)3 * D_ * D_);

    norm_idx<<<1, 64, 0, stream>>>(idxraw, nidx);
    convert_x<<<dim3(SD / (256 * 8)), dim3(256), 0, stream>>>(x, xb);
    transpose_w<<<dim3(24, 24, 3), dim3(32, 8), 0, stream>>>(Wq, Wk, Wv, wtws);
    qkv_gemm<<<dim3(32, 18), dim3(256), 0, stream>>>(xb, wtws, bq, bk, bv, qws, kws, vcws);
    attn_kernel<<<dim3(128, 16, 2), dim3(256), 0, stream>>>(nidx, qws, kws, vcws, out);
}